// Round 11
// baseline (522.068 us; speedup 1.0000x reference)
//
#include <hip/hip_runtime.h>
#include <hip/hip_bf16.h>

// NGCF forward on MI355X.
// r18: COLUMN-BLOCK-ORDERED edge lists for L2 phase coherence. History:
//  r12 fused 1 tile/wave, weights in L2                         -> 571 (119us/layer)
//  r13/r14/r15 source-level scheduling tricks                   -> REGRESS (spills)
//  r16 fine-grain: 1 tile per 4-wave block, grid 9375           -> 527 (102us/layer)
//  r17 clean-round bins + prod-from-bf16                        -> 521 BEST (100us/layer)
// k_layer diagnosis (r17 counters): occ 79 / VALU 40 / Mfma 1 / fetch 2.9TB/s
// -- nothing saturated, yet Little's law says the gather should finish ~10x
// faster at nominal L3 latency => the L2-miss path is QUEUE-LIMITED; time
// tracks miss traffic (284MB of 614MB logical = 54% hit). Lever = L2 hit
// rate. r18: sortbucket's counting-sort key becomes (lr, col>>15) -- each
// row's edges ordered by 5 column-blocks of 32768 rows (4MB slice, exactly
// one XCD L2). k_layer is UNCHANGED: concurrently-resident blocks sweep
// col-blocks in loose lockstep (similar degrees -> similar progress), so the
// live gather working set becomes ~1-2 slices instead of 19.2MB. Within-row
// sum order changes -- already nondeterministic (atomic scatter; absmax
// pinned at 2^-8 for 10 rounds). sortbucket LDS stays 38.4KB (hist reused
// in-place as cursor; in-place scan) -> occupancy unchanged.
// CSR build (r8/r9/r17): two-level bucket binning with LDS repack, int4
// edge loads, reservation-atomic latency hidden, clean-round grids.

#define N_USER 100000
#define N_ITEM 50000
#define N_NODES 150000
#define NE 4800000
#define D 64
#define BROWS 128
#define NBUCK ((N_NODES + BROWS - 1) / BROWS)  // 1172
#define BCAP 4480                               // per-bucket: mean 4096 + 6 sigma
#define NG (N_NODES / 16)                       // 9375 row-tiles of 16 (exact)
#define NCB 5                                   // column-blocks of 32768 (col>>15)
#define NBIN (BROWS * NCB)                      // 640 sort bins

// two-level binning
#define SUPSH 12                                // super = row >> 12 (4096 rows)
#define NSUP 37
#define SCAP 133120                             // per-super: mean 131072 + ~5.7 sigma
#define STG1 (NSUP * SCAP)                      // 4,925,440 >= NE
#define CH1 4688                                // edges per bin1 block -> B1 = 1024 EXACT
#define B1 ((NE + CH1 - 1) / CH1)               // 1024 = one clean resident round
#define CPS 27                                  // chunks per super (bin2)
#define CH2 4931                                // 27*4931 = 133137 >= SCAP
#define B2 (NSUP * CPS)                         // 999 blocks ~ one clean round

typedef __hip_bfloat16 bf16;
typedef unsigned short u16;
typedef __attribute__((ext_vector_type(8))) short short8;
typedef __attribute__((ext_vector_type(4))) float float4v;

__device__ __forceinline__ float bits2f(u16 u) {
  return __uint_as_float(((unsigned int)u) << 16);
}
__device__ __forceinline__ u16 f2bits(float x) {
  union { bf16 h; u16 u; } c;
  c.h = __float2bfloat16(x);
  return c.u;
}
__device__ __forceinline__ float loadF(const void* p, long i, int f32) {
  if (f32) return ((const float*)p)[i];
  return bits2f(((const u16*)p)[i]);
}

__global__ void k_zero(int* __restrict__ p, int n) {
  int i = blockIdx.x * blockDim.x + threadIdx.x;
  if (i < n) p[i] = 0;
}

// flag <- 1 if the float buffers are float32, 0 if bf16.
__global__ void k_detect(const u16* __restrict__ ue, int* __restrict__ flag) {
  int bad = 0;
  for (int t = threadIdx.x; t < 512; t += 256) {
    float f = fabsf(bits2f(ue[t]));
    if (!(f < 1e4f)) bad = 1;  // catches NaN/Inf too
  }
  if (bad) atomicOr(flag, 1);
}

// Pre-pack frag-ordered bf16 weights (one block per layer) + combined bias.
// wfrag[layer][f]: f = ((t*4+s2)*64+lane)*8+j maps to W[k][n],
// k = s2*32+(lane>>4)*8+j (in [Wgc;Wbi]), n = t*16+(lane&15).
__global__ void k_prepw(const void* __restrict__ Wgc, const void* __restrict__ bgc,
                        const void* __restrict__ Wbi, const void* __restrict__ bbi,
                        u16* __restrict__ wfrag, float* __restrict__ biasws,
                        const int* __restrict__ flag) {
  int f32 = *flag;
  int layer = blockIdx.x;
  for (int f = threadIdx.x; f < 8192; f += 512) {
    int j = f & 7;
    int lane = (f >> 3) & 63;
    int s2 = (f >> 9) & 3;
    int t = f >> 11;
    int k = s2 * 32 + (lane >> 4) * 8 + j;
    int n = t * 16 + (lane & 15);
    float w = (k < 64) ? loadF(Wgc, (long)layer * 4096 + k * 64 + n, f32)
                       : loadF(Wbi, (long)layer * 4096 + (k - 64) * 64 + n, f32);
    wfrag[layer * 8192 + f] = f2bits(w);
  }
  if (threadIdx.x < 64)
    biasws[layer * 64 + threadIdx.x] =
        loadF(bgc, layer * 64 + threadIdx.x, f32) +
        loadF(bbi, layer * 64 + threadIdx.x, f32);
}

// ego32[N,64] fp32 and egobf[N,64] bf16 <- concat(user_emb, item_emb)
__global__ void k_init(const void* __restrict__ ue, const void* __restrict__ ie,
                       float* __restrict__ ego32, u16* __restrict__ egobf,
                       const int* __restrict__ flag) {
  int f32 = *flag;
  int i4 = (blockIdx.x * blockDim.x + threadIdx.x) * 4;
  if (i4 >= N_NODES * D) return;
  const int UD = N_USER * D;
  float4 v;
  ushort4 b;
  if (f32) {
    const float* s = (i4 < UD) ? ((const float*)ue + i4) : ((const float*)ie + (i4 - UD));
    v = *(const float4*)s;
    b = make_ushort4(f2bits(v.x), f2bits(v.y), f2bits(v.z), f2bits(v.w));
  } else {
    const u16* s = (i4 < UD) ? ((const u16*)ue + i4) : ((const u16*)ie + (i4 - UD));
    b = *(const ushort4*)s;
    v = make_float4(bits2f(b.x), bits2f(b.y), bits2f(b.z), bits2f(b.w));
  }
  *(float4*)(ego32 + i4) = v;
  *(ushort4*)(egobf + i4) = b;
}

// Level 1: bin a CH1-edge chunk into NSUP super-buckets. Scatter into LDS
// (counting-sort order by super), then write each super's run coalesced into
// staged1[super][SCAP]. Entry: (lr12<<18 | col, val_bits), lr12 = row & 4095.
__global__ void __launch_bounds__(512, 8) k_bin1(
    const int* __restrict__ row, const int* __restrict__ col,
    const void* __restrict__ val, int* __restrict__ scnt,
    int2* __restrict__ staged1, const int* __restrict__ flag) {
  __shared__ int2 sbuf[CH1];                 // 36.6 KB
  __shared__ int hist[NSUP];
  __shared__ int lstart[NSUP];
  __shared__ int gbase[NSUP];
  __shared__ int lcur[NSUP];
  int f32 = *flag;
  int tid = threadIdx.x;
  int e0 = blockIdx.x * CH1;
  int e1 = min(e0 + CH1, NE);               // e1-e0 always a multiple of 4
  if (tid < NSUP) hist[tid] = 0;
  __syncthreads();
  // pass 1: histogram over supers, 4 edges/thread (int4)
  for (int e = e0 + tid * 4; e < e1; e += 512 * 4) {
    int4 r4 = *(const int4*)(row + e);
    atomicAdd(&hist[r4.x >> SUPSH], 1);
    atomicAdd(&hist[r4.y >> SUPSH], 1);
    atomicAdd(&hist[r4.z >> SUPSH], 1);
    atomicAdd(&hist[r4.w >> SUPSH], 1);
  }
  __syncthreads();
  // wave 0: exclusive scan of hist; issue the global reservation atomic into
  // a register (committed to LDS only after the scatter -> latency hidden)
  int resv = 0;
  if (tid < 64) {
    int h = (tid < NSUP) ? hist[tid] : 0;
    int inc = h;
#pragma unroll
    for (int off = 1; off < 64; off <<= 1) {
      int v = __shfl_up(inc, off);
      if (tid >= off) inc += v;
    }
    if (tid < NSUP) {
      int ex = inc - h;
      lstart[tid] = ex;
      lcur[tid] = ex;
      if (h) resv = atomicAdd(&scnt[tid], h);
    }
  }
  __syncthreads();
  // pass 2: scatter into LDS in super-sorted order, 4 edges/thread
  for (int e = e0 + tid * 4; e < e1; e += 512 * 4) {
    int4 r4 = *(const int4*)(row + e);
    int4 c4 = *(const int4*)(col + e);
    int vb[4];
    if (f32) {
      float4 v4 = *(const float4*)((const float*)val + e);
      vb[0] = __float_as_int(v4.x); vb[1] = __float_as_int(v4.y);
      vb[2] = __float_as_int(v4.z); vb[3] = __float_as_int(v4.w);
    } else {
      ushort4 v4 = *(const ushort4*)((const u16*)val + e);
      vb[0] = __float_as_int(bits2f(v4.x)); vb[1] = __float_as_int(bits2f(v4.y));
      vb[2] = __float_as_int(bits2f(v4.z)); vb[3] = __float_as_int(bits2f(v4.w));
    }
    int rr[4] = {r4.x, r4.y, r4.z, r4.w};
    int cc[4] = {c4.x, c4.y, c4.z, c4.w};
#pragma unroll
    for (int j = 0; j < 4; ++j) {
      int s = rr[j] >> SUPSH;
      int pos = atomicAdd(&lcur[s], 1);
      sbuf[pos] = make_int2(((rr[j] & 4095) << 18) | cc[j], vb[j]);
    }
  }
  // commit reservations (atomic result consumed here, after scatter)
  if (tid < NSUP) gbase[tid] = resv;
  __syncthreads();
  // coalesced dense copy of each super's run; waves split the supers
  int wv = tid >> 6;
  int ln = tid & 63;
  for (int s = wv; s < NSUP; s += 8) {
    int h = hist[s];
    int gb = gbase[s];
    int ls = lstart[s];
    if (gb + h > SCAP) h = max(0, SCAP - gb);
    int2* dst = staged1 + (size_t)s * SCAP + gb;
    for (int i = ln; i < h; i += 64) dst[i] = sbuf[ls + i];
  }
}

// Level 2: re-bin one CH2-entry chunk of a super segment into its 32 row-
// buckets (global bucket = super*32 + (lr12>>7)), LDS repack, coalesced dense
// write into staged2[bucket][BCAP]. Output entry: (lr7<<18 | col, val_bits).
__global__ void __launch_bounds__(512, 8) k_bin2(
    const int* __restrict__ scnt, const int2* __restrict__ staged1,
    int* __restrict__ bcnt, int2* __restrict__ staged2) {
  __shared__ int2 sbuf[CH2];                 // 38.5 KB
  __shared__ int hist[32];
  __shared__ int lstart[32];
  __shared__ int gbase[32];
  __shared__ int lcur[32];
  int tid = threadIdx.x;
  int sup = blockIdx.x / CPS;
  int e0 = (blockIdx.x % CPS) * CH2;
  int n = min(scnt[sup], SCAP);
  int e1 = min(e0 + CH2, n);
  if (e0 >= e1) return;  // uniform across block
  const int2* seg = staged1 + (size_t)sup * SCAP;
  if (tid < 32) hist[tid] = 0;
  __syncthreads();
  // histogram, 2 entries/thread (int4 over int2 pairs); e1 may be odd
  {
    int e = e0 + tid * 2;
    for (; e + 1 < e1; e += 1024) {
      int4 two = *(const int4*)(seg + e);
      atomicAdd(&hist[two.x >> 25], 1);
      atomicAdd(&hist[two.z >> 25], 1);
    }
    if (e < e1) atomicAdd(&hist[seg[e].x >> 25], 1);
  }
  __syncthreads();
  int resv = 0;
  if (tid < 64) {
    int h = (tid < 32) ? hist[tid & 31] : 0;
    int inc = h;
#pragma unroll
    for (int off = 1; off < 32; off <<= 1) {
      int v = __shfl_up(inc, off);
      if (tid >= off) inc += v;
    }
    if (tid < 32) {
      int ex = inc - h;
      lstart[tid] = ex;
      lcur[tid] = ex;
      if (h) resv = atomicAdd(&bcnt[sup * 32 + tid], h);
    }
  }
  __syncthreads();
  // scatter into LDS in bucket-sorted order, 2 entries/thread
  {
    int e = e0 + tid * 2;
    for (; e + 1 < e1; e += 1024) {
      int4 two = *(const int4*)(seg + e);
      int lb0 = two.x >> 25;
      int p0 = atomicAdd(&lcur[lb0], 1);
      sbuf[p0] = make_int2(two.x & 0x01FFFFFF, two.y);
      int lb1 = two.z >> 25;
      int p1 = atomicAdd(&lcur[lb1], 1);
      sbuf[p1] = make_int2(two.z & 0x01FFFFFF, two.w);
    }
    if (e < e1) {
      int2 ent = seg[e];
      int lb = ent.x >> 25;
      int pos = atomicAdd(&lcur[lb], 1);
      sbuf[pos] = make_int2(ent.x & 0x01FFFFFF, ent.y);
    }
  }
  if (tid < 32) gbase[tid] = resv;
  __syncthreads();
  // coalesced dense copy of each bucket's run; waves split the buckets
  int wv = tid >> 6;
  int ln = tid & 63;
  for (int lb = wv; lb < 32; lb += 8) {
    int h = hist[lb];
    int gb = gbase[lb];
    int ls = lstart[lb];
    int b = sup * 32 + lb;
    if (b >= NBUCK) continue;       // unreachable given row bounds; safety
    if (gb + h > BCAP) h = max(0, BCAP - gb);
    int2* dst = staged2 + (size_t)b * BCAP + gb;
    for (int i = ln; i < h; i += 64) dst[i] = sbuf[ls + i];
  }
}

// Exclusive scan of per-bucket totals -> bbase[NBUCK]. One block of 1024.
__global__ void __launch_bounds__(1024) k_bucketbase(const int* __restrict__ bcnt,
                                                     int* __restrict__ bbase) {
  __shared__ int sh[2048];
  int tid = threadIdx.x;
  int t0 = (tid < NBUCK) ? min(bcnt[tid], BCAP) : 0;
  int i1 = 1024 + tid;
  int t1 = (i1 < NBUCK) ? min(bcnt[i1], BCAP) : 0;
  sh[tid] = t0;
  sh[i1] = t1;
  __syncthreads();
  for (int off = 1; off < 2048; off <<= 1) {
    int a0 = (tid >= off) ? sh[tid - off] : 0;
    int a1 = (i1 >= off) ? sh[i1 - off] : 0;
    __syncthreads();
    sh[tid] += a0;
    sh[i1] += a1;
    __syncthreads();
  }
  if (tid < NBUCK) bbase[tid] = sh[tid] - t0;       // exclusive
  if (i1 < NBUCK) bbase[i1] = sh[i1] - t1;
}

// One block per bucket: LDS counting sort of the bucket's staged edges by
// key (lr, col>>15) -- row-major, column-block minor (NCB=5 blocks of 32768
// cols = one 4MB egobf slice each). Rows stay contiguous (rp unchanged);
// within a row, edges are ordered by column-block so concurrently-running
// k_layer blocks sweep L2-sized gather slices in loose phase coherence.
// hist is reused in place as the scatter cursor -> LDS stays 38.4KB.
__global__ void __launch_bounds__(512, 8) k_sortbucket(
    const int* __restrict__ bcnt, const int2* __restrict__ staged,
    const int* __restrict__ bbase, int* __restrict__ rp, int2* __restrict__ csr) {
  __shared__ int2 sbuf[BCAP];      // 35.8 KB
  __shared__ int hist[NBIN];       // 2.56 KB; becomes cursor after scan
  int tid = threadIdx.x;
  int b = blockIdx.x;
  for (int i = tid; i < NBIN; i += 512) hist[i] = 0;
  __syncthreads();

  int n = min(bcnt[b], BCAP);
  const int2* seg = staged + (size_t)b * BCAP;
  {
    int e = tid * 2;
    for (; e + 1 < n; e += 1024) {
      int4 two = *(const int4*)(seg + e);
      atomicAdd(&hist[(two.x >> 18) * NCB + ((two.x >> 15) & 7)], 1);
      atomicAdd(&hist[(two.z >> 18) * NCB + ((two.z >> 15) & 7)], 1);
    }
    if (e < n) {
      int x = seg[e].x;
      atomicAdd(&hist[(x >> 18) * NCB + ((x >> 15) & 7)], 1);
    }
  }
  __syncthreads();

  // capture originals, then in-place inclusive Hillis-Steele scan over NBIN
  int i0 = tid, i1 = tid + 512;
  int h0 = hist[i0];
  int h1 = (i1 < NBIN) ? hist[i1] : 0;
  for (int off = 1; off < NBIN; off <<= 1) {
    int v0 = (i0 >= off) ? hist[i0 - off] : 0;
    int v1 = (i1 < NBIN && i1 >= off) ? hist[i1 - off] : 0;
    __syncthreads();
    hist[i0] += v0;
    if (i1 < NBIN) hist[i1] += v1;
    __syncthreads();
  }
  // hist -> exclusive starts (cursor)
  hist[i0] -= h0;
  if (i1 < NBIN) hist[i1] -= h1;
  __syncthreads();

  int base_b = bbase[b];
  if (tid < BROWS) {
    int r = b * BROWS + tid;
    if (r < N_NODES) rp[r] = base_b + hist[tid * NCB];  // row start = its first bin
  }
  if (b == 0 && tid == 0) rp[N_NODES] = NE;
  __syncthreads();   // rp reads done before scatter mutates cursor

  {
    int e = tid * 2;
    for (; e + 1 < n; e += 1024) {
      int4 two = *(const int4*)(seg + e);
      int k0 = (two.x >> 18) * NCB + ((two.x >> 15) & 7);
      int p0 = atomicAdd(&hist[k0], 1);
      if (p0 < BCAP) sbuf[p0] = make_int2(two.x & 0x3FFFF, two.y);
      int k1 = (two.z >> 18) * NCB + ((two.z >> 15) & 7);
      int p1 = atomicAdd(&hist[k1], 1);
      if (p1 < BCAP) sbuf[p1] = make_int2(two.z & 0x3FFFF, two.w);
    }
    if (e < n) {
      int2 ent = seg[e];
      int k = (ent.x >> 18) * NCB + ((ent.x >> 15) & 7);
      int pos = atomicAdd(&hist[k], 1);
      if (pos < BCAP) sbuf[pos] = make_int2(ent.x & 0x3FFFF, ent.y);
    }
  }
  __syncthreads();

  for (int i = tid; i < n; i += 512) csr[(size_t)base_b + i] = sbuf[i];
}

// FUSED layer (r16/r17 structure, UNCHANGED in r18): ONE 16-row tile per
// 4-wave 256-thread block. Wave wv runs SpMM pass p=wv (rows tg*16 + wv*4 +
// quad; 16 lanes consume full 128B neighbor rows, csr broadcast within
// quarter-wave), depositing bf16 [side|prod] into the block-shared LDS tile
// (272B row stride -> <=2-way bank alias, free). prod sourced from egobf_i.
// __syncthreads, then wave wv computes its t=wv column-slice: 4 MFMAs
// (B-frags 16B global loads from L2-resident wfrag), writes cols [wv*16,+16).
__global__ void __launch_bounds__(256, 8) k_layer(
    const int* __restrict__ rp, const int2* __restrict__ csr,
    const u16* __restrict__ egobf_i,
    const u16* __restrict__ wfrag, const float* __restrict__ biasws,
    float* __restrict__ ego32_o, u16* __restrict__ egobf_o, int layer) {
  __shared__ u16 tile[2176];       // 16 rows x 136 u16 (272B stride), 4.25KB
  int tid = threadIdx.x;
  int lane = tid & 63;
  int ln = lane & 15;
  int quad = lane >> 4;            // 0..3
  int wv = tid >> 6;               // 0..3 = SpMM pass index = MFMA t-slice
  int tg = blockIdx.x;             // tile index (16 rows); grid == NG
  const u16* wf = wfrag + layer * 8192;

  // ---- phase 1: SpMM pass wv (4 rows, quarter-wave per row) ----
  {
    int r = tg * 16 + wv * 4 + quad;
    int s = rp[r];
    int e = rp[r + 1];
    float4 acc = make_float4(0.f, 0.f, 0.f, 0.f);
    int i = s;
    for (; i + 8 <= e; i += 8) {
      int2 cc[8];
#pragma unroll
      for (int t = 0; t < 8; ++t) cc[t] = csr[i + t];
      ushort4 gg[8];
#pragma unroll
      for (int t = 0; t < 8; ++t)
        gg[t] = *(const ushort4*)(egobf_i + (size_t)cc[t].x * 64 + ln * 4);
#pragma unroll
      for (int t = 0; t < 8; ++t) {
        float v = __int_as_float(cc[t].y);
        acc.x += v * bits2f(gg[t].x);
        acc.y += v * bits2f(gg[t].y);
        acc.z += v * bits2f(gg[t].z);
        acc.w += v * bits2f(gg[t].w);
      }
    }
    for (; i < e; ++i) {
      int2 c = csr[i];
      ushort4 g = *(const ushort4*)(egobf_i + (size_t)c.x * 64 + ln * 4);
      float v = __int_as_float(c.y);
      acc.x += v * bits2f(g.x);
      acc.y += v * bits2f(g.y);
      acc.z += v * bits2f(g.z);
      acc.w += v * bits2f(g.w);
    }
    // own-row ego from bf16
    ushort4 eb = *(const ushort4*)(egobf_i + (size_t)r * 64 + ln * 4);
    float4 er = make_float4(bits2f(eb.x), bits2f(eb.y), bits2f(eb.z), bits2f(eb.w));
    // deposit [side|prod] into shared tile row (wv*4+quad)
    u16* trow = tile + (wv * 4 + quad) * 136;
    *(ushort4*)(trow + ln * 4) =
        make_ushort4(f2bits(acc.x), f2bits(acc.y), f2bits(acc.z), f2bits(acc.w));
    *(ushort4*)(trow + 64 + ln * 4) =
        make_ushort4(f2bits(er.x * acc.x), f2bits(er.y * acc.y),
                     f2bits(er.z * acc.z), f2bits(er.w * acc.w));
  }
  __syncthreads();                 // tile complete across the 4 waves

  // ---- phase 2: wave wv computes t=wv slice: 16 rows x 16 cols ----
  float4v acc2 = (float4v){0.f, 0.f, 0.f, 0.f};
#pragma unroll
  for (int s2 = 0; s2 < 4; ++s2) {
    short8 A = *(const short8*)(tile + (size_t)ln * 136 + s2 * 32 + quad * 8);
    short8 Bf = *(const short8*)(wf + ((size_t)((wv * 4 + s2) * 64 + lane)) * 8);
    acc2 = __builtin_amdgcn_mfma_f32_16x16x32_bf16(A, Bf, acc2, 0, 0, 0);
  }
  int r0 = tg * 16;
  float bt = biasws[layer * 64 + wv * 16 + ln];
#pragma unroll
  for (int g2 = 0; g2 < 4; ++g2) {
    float x = acc2[g2] + bt;
    x = fmaxf(x, 0.2f * x);        // leaky_relu(0.2)
    size_t idx = (size_t)(r0 + quad * 4 + g2) * 64 + wv * 16 + ln;
    ego32_o[idx] = x;
    egobf_o[idx] = f2bits(x);
  }
}

// gather 8192 output rows into out slice; optional l2-normalize per row.
__global__ void k_gather(const float* __restrict__ ego, const int* __restrict__ users,
                         const int* __restrict__ items, void* __restrict__ out,
                         int slice, int do_norm, const int* __restrict__ flag) {
  int f32 = *flag;
  int b = blockIdx.x * 4 + (threadIdx.x >> 6);
  int lane = threadIdx.x & 63;
  if (b >= 8192) return;
  int r = (b < 4096) ? users[b] : (N_USER + items[b - 4096]);
  float x = ego[(size_t)r * D + lane];
  float scale = 1.f;
  if (do_norm) {
    float ss = x * x;
    for (int off = 32; off > 0; off >>= 1) ss += __shfl_xor(ss, off);
    scale = 1.f / fmaxf(sqrtf(ss), 1e-12f);
  }
  float y = x * scale;
  long idx = (long)b * 256 + slice * 64 + lane;
  if (f32) ((float*)out)[idx] = y;
  else ((bf16*)out)[idx] = __float2bfloat16(y);
}

extern "C" void kernel_launch(void* const* d_in, const int* in_sizes, int n_in,
                              void* d_out, int out_size, void* d_ws, size_t ws_size,
                              hipStream_t stream) {
  const void* ue = d_in[0];
  const void* ie = d_in[1];
  const void* Wgc = d_in[2];
  const void* bgc = d_in[3];
  const void* Wbi = d_in[4];
  const void* bbi = d_in[5];
  const void* aval = d_in[6];
  const int* arow = (const int*)d_in[7];
  const int* acol = (const int*)d_in[8];
  const int* users = (const int*)d_in[9];
  const int* items = (const int*)d_in[10];

  char* ws = (char*)d_ws;
  size_t off = 0;
  float* ego32a = (float*)(ws + off); off += (size_t)N_NODES * D * 4;     // 38.4 MB
  u16* egobfa = (u16*)(ws + off);     off += (size_t)N_NODES * D * 2;     // 19.2 MB
  float* ego32b = (float*)(ws + off); off += (size_t)N_NODES * D * 4;     // 38.4 MB
  u16* egobfb = (u16*)(ws + off);     off += (size_t)N_NODES * D * 2;     // 19.2 MB
  int2* staged = (int2*)(ws + off);   off += (size_t)NBUCK * BCAP * 8;    // 42.0 MB
  int2* csr = (int2*)(ws + off);      off += (size_t)STG1 * 8;            // 39.4 MB (aliases level-1 staging)
  int* rp = (int*)(ws + off);         off += (size_t)(N_NODES + 64) * 4;
  int* bcnt = (int*)(ws + off);       off += (size_t)NBUCK * 4;
  int* scnt = (int*)(ws + off);       off += 64 * 4;                      // contiguous after bcnt
  int* bbase = (int*)(ws + off);      off += (size_t)(NBUCK + 64) * 4;
  int* flag = (int*)(ws + off);       off += 256;
  u16* wfrag = (u16*)(ws + off);      off += 3 * 8192 * 2;                // 48 KB frag-ordered weights
  float* biasws = (float*)(ws + off); off += 3 * 64 * 4;                  // combined bias
  int2* staged1 = csr;                // level-1 staging aliases csr (dead until sortbucket)
  (void)ws_size;

  k_zero<<<1, 64, 0, stream>>>(flag, 1);
  k_detect<<<1, 256, 0, stream>>>((const u16*)ue, flag);
  k_zero<<<(NBUCK + 64 + 255) / 256, 256, 0, stream>>>(bcnt, NBUCK + 64);  // bcnt + scnt
  k_prepw<<<3, 512, 0, stream>>>(Wgc, bgc, Wbi, bbi, wfrag, biasws, flag);
  k_init<<<(N_NODES * D / 4 + 255) / 256, 256, 0, stream>>>(ue, ie, ego32a, egobfa, flag);
  // slice 0 = raw (un-normalized) initial ego
  k_gather<<<2048, 256, 0, stream>>>(ego32a, users, items, d_out, 0, 0, flag);
  k_bin1<<<B1, 512, 0, stream>>>(arow, acol, aval, scnt, staged1, flag);
  k_bin2<<<B2, 512, 0, stream>>>(scnt, staged1, bcnt, staged);
  k_bucketbase<<<1, 1024, 0, stream>>>(bcnt, bbase);
  k_sortbucket<<<NBUCK, 512, 0, stream>>>(bcnt, staged, bbase, rp, csr);

  float* ei32 = ego32a; u16* eibf = egobfa;
  float* eo32 = ego32b; u16* eobf = egobfb;
  for (int k = 0; k < 3; ++k) {
    k_layer<<<NG, 256, 0, stream>>>(rp, csr, eibf, wfrag, biasws,
                                    eo32, eobf, k);
    k_gather<<<2048, 256, 0, stream>>>(eo32, users, items, d_out, k + 1, 1, flag);
    float* t32 = ei32; ei32 = eo32; eo32 = t32;
    u16* tbf = eibf; eibf = eobf; eobf = tbf;
  }
}

// Round 12
// 506.142 us; speedup vs baseline: 1.0315x; 1.0315x over previous
//
#include <hip/hip_runtime.h>
#include <hip/hip_bf16.h>

// NGCF forward on MI355X.
// r19: DEAD-WRITE ELISION via gather-set bitmap. History:
//  r12 fused 1 tile/wave, weights in L2                         -> 571 (119us/layer)
//  r13/r14/r15 source-level scheduling tricks                   -> REGRESS (spills)
//  r16 fine-grain: 1 tile per 4-wave block, grid 9375           -> 527 (102us/layer)
//  r17 clean-round bins + prod-from-bf16                        -> 521 (100us/layer)
//  r18 column-block edge order: NULL (FETCH 284->283; block start
//      stagger defeats phase coherence; order kept, harmless)   -> 522
// k_layer regime: 283MB FETCH = L2-miss traffic mostly L3-served (~3.4TB/s
// fabric); nothing saturated -> time tracks total past-L2 traffic. Remaining
// reducible traffic = DEAD WRITES: ego32_o (38.4MB/layer fp32) is read by
// k_gather for only <=8192 mapped rows (2MB) -- 95% dead; layer-2 egobf_o
// (19.2MB) is never read at all. r19: 18.8KB row bitmap of users u items
// (built by one tiny block); k_init/k_layer write ego32 only for bitmap
// rows; k_layer skips egobf_o on the last layer. Written values are
// BIT-IDENTICAL to r17/r18 (only dead stores elided) -> absmax unchanged.
// CSR build (r8/r9/r17/r18): two-level bucket binning with LDS repack, int4
// edge loads, reservation-atomic latency hidden, clean-round grids,
// (lr,col-block) sort key.

#define N_USER 100000
#define N_ITEM 50000
#define N_NODES 150000
#define NE 4800000
#define D 64
#define BROWS 128
#define NBUCK ((N_NODES + BROWS - 1) / BROWS)  // 1172
#define BCAP 4480                               // per-bucket: mean 4096 + 6 sigma
#define NG (N_NODES / 16)                       // 9375 row-tiles of 16 (exact)
#define NCB 5                                   // column-blocks of 32768 (col>>15)
#define NBIN (BROWS * NCB)                      // 640 sort bins
#define GMW ((N_NODES + 31) / 32)               // 4688 bitmap words

// two-level binning
#define SUPSH 12                                // super = row >> 12 (4096 rows)
#define NSUP 37
#define SCAP 133120                             // per-super: mean 131072 + ~5.7 sigma
#define STG1 (NSUP * SCAP)                      // 4,925,440 >= NE
#define CH1 4688                                // edges per bin1 block -> B1 = 1024 EXACT
#define B1 ((NE + CH1 - 1) / CH1)               // 1024 = one clean resident round
#define CPS 27                                  // chunks per super (bin2)
#define CH2 4931                                // 27*4931 = 133137 >= SCAP
#define B2 (NSUP * CPS)                         // 999 blocks ~ one clean round

typedef __hip_bfloat16 bf16;
typedef unsigned short u16;
typedef unsigned int u32;
typedef __attribute__((ext_vector_type(8))) short short8;
typedef __attribute__((ext_vector_type(4))) float float4v;

__device__ __forceinline__ float bits2f(u16 u) {
  return __uint_as_float(((unsigned int)u) << 16);
}
__device__ __forceinline__ u16 f2bits(float x) {
  union { bf16 h; u16 u; } c;
  c.h = __float2bfloat16(x);
  return c.u;
}
__device__ __forceinline__ float loadF(const void* p, long i, int f32) {
  if (f32) return ((const float*)p)[i];
  return bits2f(((const u16*)p)[i]);
}

__global__ void k_zero(int* __restrict__ p, int n) {
  int i = blockIdx.x * blockDim.x + threadIdx.x;
  if (i < n) p[i] = 0;
}

// flag <- 1 if the float buffers are float32, 0 if bf16.
__global__ void k_detect(const u16* __restrict__ ue, int* __restrict__ flag) {
  int bad = 0;
  for (int t = threadIdx.x; t < 512; t += 256) {
    float f = fabsf(bits2f(ue[t]));
    if (!(f < 1e4f)) bad = 1;  // catches NaN/Inf too
  }
  if (bad) atomicOr(flag, 1);
}

// Build gather-set bitmap: rows in users u (N_USER+items). ONE block
// (zero + mark in the same block; no cross-block race).
__global__ void __launch_bounds__(1024) k_mark(const int* __restrict__ users,
                                               const int* __restrict__ items,
                                               u32* __restrict__ gmap) {
  int tid = threadIdx.x;
  for (int i = tid; i < GMW; i += 1024) gmap[i] = 0;
  __syncthreads();
  for (int b = tid; b < 8192; b += 1024) {
    int r = (b < 4096) ? users[b] : (N_USER + items[b - 4096]);
    atomicOr(&gmap[r >> 5], 1u << (r & 31));
  }
}

// Pre-pack frag-ordered bf16 weights (one block per layer) + combined bias.
// wfrag[layer][f]: f = ((t*4+s2)*64+lane)*8+j maps to W[k][n],
// k = s2*32+(lane>>4)*8+j (in [Wgc;Wbi]), n = t*16+(lane&15).
__global__ void k_prepw(const void* __restrict__ Wgc, const void* __restrict__ bgc,
                        const void* __restrict__ Wbi, const void* __restrict__ bbi,
                        u16* __restrict__ wfrag, float* __restrict__ biasws,
                        const int* __restrict__ flag) {
  int f32 = *flag;
  int layer = blockIdx.x;
  for (int f = threadIdx.x; f < 8192; f += 512) {
    int j = f & 7;
    int lane = (f >> 3) & 63;
    int s2 = (f >> 9) & 3;
    int t = f >> 11;
    int k = s2 * 32 + (lane >> 4) * 8 + j;
    int n = t * 16 + (lane & 15);
    float w = (k < 64) ? loadF(Wgc, (long)layer * 4096 + k * 64 + n, f32)
                       : loadF(Wbi, (long)layer * 4096 + (k - 64) * 64 + n, f32);
    wfrag[layer * 8192 + f] = f2bits(w);
  }
  if (threadIdx.x < 64)
    biasws[layer * 64 + threadIdx.x] =
        loadF(bgc, layer * 64 + threadIdx.x, f32) +
        loadF(bbi, layer * 64 + threadIdx.x, f32);
}

// ego32[N,64] fp32 (gather rows only) and egobf[N,64] bf16 (all rows).
__global__ void k_init(const void* __restrict__ ue, const void* __restrict__ ie,
                       float* __restrict__ ego32, u16* __restrict__ egobf,
                       const int* __restrict__ flag, const u32* __restrict__ gmap) {
  int f32 = *flag;
  int i4 = (blockIdx.x * blockDim.x + threadIdx.x) * 4;
  if (i4 >= N_NODES * D) return;
  const int UD = N_USER * D;
  float4 v;
  ushort4 b;
  if (f32) {
    const float* s = (i4 < UD) ? ((const float*)ue + i4) : ((const float*)ie + (i4 - UD));
    v = *(const float4*)s;
    b = make_ushort4(f2bits(v.x), f2bits(v.y), f2bits(v.z), f2bits(v.w));
  } else {
    const u16* s = (i4 < UD) ? ((const u16*)ue + i4) : ((const u16*)ie + (i4 - UD));
    b = *(const ushort4*)s;
    v = make_float4(bits2f(b.x), bits2f(b.y), bits2f(b.z), bits2f(b.w));
  }
  int r = i4 >> 6;
  if ((gmap[r >> 5] >> (r & 31)) & 1) *(float4*)(ego32 + i4) = v;
  *(ushort4*)(egobf + i4) = b;
}

// Level 1: bin a CH1-edge chunk into NSUP super-buckets. Scatter into LDS
// (counting-sort order by super), then write each super's run coalesced into
// staged1[super][SCAP]. Entry: (lr12<<18 | col, val_bits), lr12 = row & 4095.
__global__ void __launch_bounds__(512, 8) k_bin1(
    const int* __restrict__ row, const int* __restrict__ col,
    const void* __restrict__ val, int* __restrict__ scnt,
    int2* __restrict__ staged1, const int* __restrict__ flag) {
  __shared__ int2 sbuf[CH1];                 // 36.6 KB
  __shared__ int hist[NSUP];
  __shared__ int lstart[NSUP];
  __shared__ int gbase[NSUP];
  __shared__ int lcur[NSUP];
  int f32 = *flag;
  int tid = threadIdx.x;
  int e0 = blockIdx.x * CH1;
  int e1 = min(e0 + CH1, NE);               // e1-e0 always a multiple of 4
  if (tid < NSUP) hist[tid] = 0;
  __syncthreads();
  // pass 1: histogram over supers, 4 edges/thread (int4)
  for (int e = e0 + tid * 4; e < e1; e += 512 * 4) {
    int4 r4 = *(const int4*)(row + e);
    atomicAdd(&hist[r4.x >> SUPSH], 1);
    atomicAdd(&hist[r4.y >> SUPSH], 1);
    atomicAdd(&hist[r4.z >> SUPSH], 1);
    atomicAdd(&hist[r4.w >> SUPSH], 1);
  }
  __syncthreads();
  // wave 0: exclusive scan of hist; issue the global reservation atomic into
  // a register (committed to LDS only after the scatter -> latency hidden)
  int resv = 0;
  if (tid < 64) {
    int h = (tid < NSUP) ? hist[tid] : 0;
    int inc = h;
#pragma unroll
    for (int off = 1; off < 64; off <<= 1) {
      int v = __shfl_up(inc, off);
      if (tid >= off) inc += v;
    }
    if (tid < NSUP) {
      int ex = inc - h;
      lstart[tid] = ex;
      lcur[tid] = ex;
      if (h) resv = atomicAdd(&scnt[tid], h);
    }
  }
  __syncthreads();
  // pass 2: scatter into LDS in super-sorted order, 4 edges/thread
  for (int e = e0 + tid * 4; e < e1; e += 512 * 4) {
    int4 r4 = *(const int4*)(row + e);
    int4 c4 = *(const int4*)(col + e);
    int vb[4];
    if (f32) {
      float4 v4 = *(const float4*)((const float*)val + e);
      vb[0] = __float_as_int(v4.x); vb[1] = __float_as_int(v4.y);
      vb[2] = __float_as_int(v4.z); vb[3] = __float_as_int(v4.w);
    } else {
      ushort4 v4 = *(const ushort4*)((const u16*)val + e);
      vb[0] = __float_as_int(bits2f(v4.x)); vb[1] = __float_as_int(bits2f(v4.y));
      vb[2] = __float_as_int(bits2f(v4.z)); vb[3] = __float_as_int(bits2f(v4.w));
    }
    int rr[4] = {r4.x, r4.y, r4.z, r4.w};
    int cc[4] = {c4.x, c4.y, c4.z, c4.w};
#pragma unroll
    for (int j = 0; j < 4; ++j) {
      int s = rr[j] >> SUPSH;
      int pos = atomicAdd(&lcur[s], 1);
      sbuf[pos] = make_int2(((rr[j] & 4095) << 18) | cc[j], vb[j]);
    }
  }
  // commit reservations (atomic result consumed here, after scatter)
  if (tid < NSUP) gbase[tid] = resv;
  __syncthreads();
  // coalesced dense copy of each super's run; waves split the supers
  int wv = tid >> 6;
  int ln = tid & 63;
  for (int s = wv; s < NSUP; s += 8) {
    int h = hist[s];
    int gb = gbase[s];
    int ls = lstart[s];
    if (gb + h > SCAP) h = max(0, SCAP - gb);
    int2* dst = staged1 + (size_t)s * SCAP + gb;
    for (int i = ln; i < h; i += 64) dst[i] = sbuf[ls + i];
  }
}

// Level 2: re-bin one CH2-entry chunk of a super segment into its 32 row-
// buckets (global bucket = super*32 + (lr12>>7)), LDS repack, coalesced dense
// write into staged2[bucket][BCAP]. Output entry: (lr7<<18 | col, val_bits).
__global__ void __launch_bounds__(512, 8) k_bin2(
    const int* __restrict__ scnt, const int2* __restrict__ staged1,
    int* __restrict__ bcnt, int2* __restrict__ staged2) {
  __shared__ int2 sbuf[CH2];                 // 38.5 KB
  __shared__ int hist[32];
  __shared__ int lstart[32];
  __shared__ int gbase[32];
  __shared__ int lcur[32];
  int tid = threadIdx.x;
  int sup = blockIdx.x / CPS;
  int e0 = (blockIdx.x % CPS) * CH2;
  int n = min(scnt[sup], SCAP);
  int e1 = min(e0 + CH2, n);
  if (e0 >= e1) return;  // uniform across block
  const int2* seg = staged1 + (size_t)sup * SCAP;
  if (tid < 32) hist[tid] = 0;
  __syncthreads();
  // histogram, 2 entries/thread (int4 over int2 pairs); e1 may be odd
  {
    int e = e0 + tid * 2;
    for (; e + 1 < e1; e += 1024) {
      int4 two = *(const int4*)(seg + e);
      atomicAdd(&hist[two.x >> 25], 1);
      atomicAdd(&hist[two.z >> 25], 1);
    }
    if (e < e1) atomicAdd(&hist[seg[e].x >> 25], 1);
  }
  __syncthreads();
  int resv = 0;
  if (tid < 64) {
    int h = (tid < 32) ? hist[tid & 31] : 0;
    int inc = h;
#pragma unroll
    for (int off = 1; off < 32; off <<= 1) {
      int v = __shfl_up(inc, off);
      if (tid >= off) inc += v;
    }
    if (tid < 32) {
      int ex = inc - h;
      lstart[tid] = ex;
      lcur[tid] = ex;
      if (h) resv = atomicAdd(&bcnt[sup * 32 + tid], h);
    }
  }
  __syncthreads();
  // scatter into LDS in bucket-sorted order, 2 entries/thread
  {
    int e = e0 + tid * 2;
    for (; e + 1 < e1; e += 1024) {
      int4 two = *(const int4*)(seg + e);
      int lb0 = two.x >> 25;
      int p0 = atomicAdd(&lcur[lb0], 1);
      sbuf[p0] = make_int2(two.x & 0x01FFFFFF, two.y);
      int lb1 = two.z >> 25;
      int p1 = atomicAdd(&lcur[lb1], 1);
      sbuf[p1] = make_int2(two.z & 0x01FFFFFF, two.w);
    }
    if (e < e1) {
      int2 ent = seg[e];
      int lb = ent.x >> 25;
      int pos = atomicAdd(&lcur[lb], 1);
      sbuf[pos] = make_int2(ent.x & 0x01FFFFFF, ent.y);
    }
  }
  if (tid < 32) gbase[tid] = resv;
  __syncthreads();
  // coalesced dense copy of each bucket's run; waves split the buckets
  int wv = tid >> 6;
  int ln = tid & 63;
  for (int lb = wv; lb < 32; lb += 8) {
    int h = hist[lb];
    int gb = gbase[lb];
    int ls = lstart[lb];
    int b = sup * 32 + lb;
    if (b >= NBUCK) continue;       // unreachable given row bounds; safety
    if (gb + h > BCAP) h = max(0, BCAP - gb);
    int2* dst = staged2 + (size_t)b * BCAP + gb;
    for (int i = ln; i < h; i += 64) dst[i] = sbuf[ls + i];
  }
}

// Exclusive scan of per-bucket totals -> bbase[NBUCK]. One block of 1024.
__global__ void __launch_bounds__(1024) k_bucketbase(const int* __restrict__ bcnt,
                                                     int* __restrict__ bbase) {
  __shared__ int sh[2048];
  int tid = threadIdx.x;
  int t0 = (tid < NBUCK) ? min(bcnt[tid], BCAP) : 0;
  int i1 = 1024 + tid;
  int t1 = (i1 < NBUCK) ? min(bcnt[i1], BCAP) : 0;
  sh[tid] = t0;
  sh[i1] = t1;
  __syncthreads();
  for (int off = 1; off < 2048; off <<= 1) {
    int a0 = (tid >= off) ? sh[tid - off] : 0;
    int a1 = (i1 >= off) ? sh[i1 - off] : 0;
    __syncthreads();
    sh[tid] += a0;
    sh[i1] += a1;
    __syncthreads();
  }
  if (tid < NBUCK) bbase[tid] = sh[tid] - t0;       // exclusive
  if (i1 < NBUCK) bbase[i1] = sh[i1] - t1;
}

// One block per bucket: LDS counting sort of the bucket's staged edges by
// key (lr, col>>15) -- row-major, column-block minor. Rows stay contiguous
// (rp unchanged). hist reused in place as cursor -> LDS stays 38.4KB.
__global__ void __launch_bounds__(512, 8) k_sortbucket(
    const int* __restrict__ bcnt, const int2* __restrict__ staged,
    const int* __restrict__ bbase, int* __restrict__ rp, int2* __restrict__ csr) {
  __shared__ int2 sbuf[BCAP];      // 35.8 KB
  __shared__ int hist[NBIN];       // 2.56 KB; becomes cursor after scan
  int tid = threadIdx.x;
  int b = blockIdx.x;
  for (int i = tid; i < NBIN; i += 512) hist[i] = 0;
  __syncthreads();

  int n = min(bcnt[b], BCAP);
  const int2* seg = staged + (size_t)b * BCAP;
  {
    int e = tid * 2;
    for (; e + 1 < n; e += 1024) {
      int4 two = *(const int4*)(seg + e);
      atomicAdd(&hist[(two.x >> 18) * NCB + ((two.x >> 15) & 7)], 1);
      atomicAdd(&hist[(two.z >> 18) * NCB + ((two.z >> 15) & 7)], 1);
    }
    if (e < n) {
      int x = seg[e].x;
      atomicAdd(&hist[(x >> 18) * NCB + ((x >> 15) & 7)], 1);
    }
  }
  __syncthreads();

  // capture originals, then in-place inclusive Hillis-Steele scan over NBIN
  int i0 = tid, i1 = tid + 512;
  int h0 = hist[i0];
  int h1 = (i1 < NBIN) ? hist[i1] : 0;
  for (int off = 1; off < NBIN; off <<= 1) {
    int v0 = (i0 >= off) ? hist[i0 - off] : 0;
    int v1 = (i1 < NBIN && i1 >= off) ? hist[i1 - off] : 0;
    __syncthreads();
    hist[i0] += v0;
    if (i1 < NBIN) hist[i1] += v1;
    __syncthreads();
  }
  // hist -> exclusive starts (cursor)
  hist[i0] -= h0;
  if (i1 < NBIN) hist[i1] -= h1;
  __syncthreads();

  int base_b = bbase[b];
  if (tid < BROWS) {
    int r = b * BROWS + tid;
    if (r < N_NODES) rp[r] = base_b + hist[tid * NCB];  // row start = its first bin
  }
  if (b == 0 && tid == 0) rp[N_NODES] = NE;
  __syncthreads();   // rp reads done before scatter mutates cursor

  {
    int e = tid * 2;
    for (; e + 1 < n; e += 1024) {
      int4 two = *(const int4*)(seg + e);
      int k0 = (two.x >> 18) * NCB + ((two.x >> 15) & 7);
      int p0 = atomicAdd(&hist[k0], 1);
      if (p0 < BCAP) sbuf[p0] = make_int2(two.x & 0x3FFFF, two.y);
      int k1 = (two.z >> 18) * NCB + ((two.z >> 15) & 7);
      int p1 = atomicAdd(&hist[k1], 1);
      if (p1 < BCAP) sbuf[p1] = make_int2(two.z & 0x3FFFF, two.w);
    }
    if (e < n) {
      int2 ent = seg[e];
      int k = (ent.x >> 18) * NCB + ((ent.x >> 15) & 7);
      int pos = atomicAdd(&hist[k], 1);
      if (pos < BCAP) sbuf[pos] = make_int2(ent.x & 0x3FFFF, ent.y);
    }
  }
  __syncthreads();

  for (int i = tid; i < n; i += 512) csr[(size_t)base_b + i] = sbuf[i];
}

// FUSED layer (r16/r17 structure + r19 write gating): ONE 16-row tile per
// 4-wave 256-thread block. Wave wv runs SpMM pass p=wv (rows tg*16 + wv*4 +
// quad; 16 lanes consume full 128B neighbor rows, csr broadcast within
// quarter-wave), depositing bf16 [side|prod] into the block-shared LDS tile
// (272B row stride -> <=2-way bank alias, free). prod sourced from egobf_i.
// __syncthreads, then wave wv computes its t=wv column-slice: 4 MFMAs
// (B-frags 16B global loads from L2-resident wfrag), writes cols [wv*16,+16).
// ego32_o written ONLY for bitmap (gather-set) rows; egobf_o skipped when
// last!=0 (layer-2 egobf is never read). Written values bit-identical.
__global__ void __launch_bounds__(256, 8) k_layer(
    const int* __restrict__ rp, const int2* __restrict__ csr,
    const u16* __restrict__ egobf_i,
    const u16* __restrict__ wfrag, const float* __restrict__ biasws,
    float* __restrict__ ego32_o, u16* __restrict__ egobf_o, int layer,
    const u32* __restrict__ gmap, int last) {
  __shared__ u16 tile[2176];       // 16 rows x 136 u16 (272B stride), 4.25KB
  int tid = threadIdx.x;
  int lane = tid & 63;
  int ln = lane & 15;
  int quad = lane >> 4;            // 0..3
  int wv = tid >> 6;               // 0..3 = SpMM pass index = MFMA t-slice
  int tg = blockIdx.x;             // tile index (16 rows); grid == NG
  const u16* wf = wfrag + layer * 8192;

  // ---- phase 1: SpMM pass wv (4 rows, quarter-wave per row) ----
  {
    int r = tg * 16 + wv * 4 + quad;
    int s = rp[r];
    int e = rp[r + 1];
    float4 acc = make_float4(0.f, 0.f, 0.f, 0.f);
    int i = s;
    for (; i + 8 <= e; i += 8) {
      int2 cc[8];
#pragma unroll
      for (int t = 0; t < 8; ++t) cc[t] = csr[i + t];
      ushort4 gg[8];
#pragma unroll
      for (int t = 0; t < 8; ++t)
        gg[t] = *(const ushort4*)(egobf_i + (size_t)cc[t].x * 64 + ln * 4);
#pragma unroll
      for (int t = 0; t < 8; ++t) {
        float v = __int_as_float(cc[t].y);
        acc.x += v * bits2f(gg[t].x);
        acc.y += v * bits2f(gg[t].y);
        acc.z += v * bits2f(gg[t].z);
        acc.w += v * bits2f(gg[t].w);
      }
    }
    for (; i < e; ++i) {
      int2 c = csr[i];
      ushort4 g = *(const ushort4*)(egobf_i + (size_t)c.x * 64 + ln * 4);
      float v = __int_as_float(c.y);
      acc.x += v * bits2f(g.x);
      acc.y += v * bits2f(g.y);
      acc.z += v * bits2f(g.z);
      acc.w += v * bits2f(g.w);
    }
    // own-row ego from bf16
    ushort4 eb = *(const ushort4*)(egobf_i + (size_t)r * 64 + ln * 4);
    float4 er = make_float4(bits2f(eb.x), bits2f(eb.y), bits2f(eb.z), bits2f(eb.w));
    // deposit [side|prod] into shared tile row (wv*4+quad)
    u16* trow = tile + (wv * 4 + quad) * 136;
    *(ushort4*)(trow + ln * 4) =
        make_ushort4(f2bits(acc.x), f2bits(acc.y), f2bits(acc.z), f2bits(acc.w));
    *(ushort4*)(trow + 64 + ln * 4) =
        make_ushort4(f2bits(er.x * acc.x), f2bits(er.y * acc.y),
                     f2bits(er.z * acc.z), f2bits(er.w * acc.w));
  }
  __syncthreads();                 // tile complete across the 4 waves

  // ---- phase 2: wave wv computes t=wv slice: 16 rows x 16 cols ----
  float4v acc2 = (float4v){0.f, 0.f, 0.f, 0.f};
#pragma unroll
  for (int s2 = 0; s2 < 4; ++s2) {
    short8 A = *(const short8*)(tile + (size_t)ln * 136 + s2 * 32 + quad * 8);
    short8 Bf = *(const short8*)(wf + ((size_t)((wv * 4 + s2) * 64 + lane)) * 8);
    acc2 = __builtin_amdgcn_mfma_f32_16x16x32_bf16(A, Bf, acc2, 0, 0, 0);
  }
  int r0 = tg * 16;
  float bt = biasws[layer * 64 + wv * 16 + ln];
#pragma unroll
  for (int g2 = 0; g2 < 4; ++g2) {
    int rr = r0 + quad * 4 + g2;
    float x = acc2[g2] + bt;
    x = fmaxf(x, 0.2f * x);        // leaky_relu(0.2)
    size_t idx = (size_t)rr * 64 + wv * 16 + ln;
    if ((gmap[rr >> 5] >> (rr & 31)) & 1) ego32_o[idx] = x;
    if (!last) egobf_o[idx] = f2bits(x);
  }
}

// gather 8192 output rows into out slice; optional l2-normalize per row.
__global__ void k_gather(const float* __restrict__ ego, const int* __restrict__ users,
                         const int* __restrict__ items, void* __restrict__ out,
                         int slice, int do_norm, const int* __restrict__ flag) {
  int f32 = *flag;
  int b = blockIdx.x * 4 + (threadIdx.x >> 6);
  int lane = threadIdx.x & 63;
  if (b >= 8192) return;
  int r = (b < 4096) ? users[b] : (N_USER + items[b - 4096]);
  float x = ego[(size_t)r * D + lane];
  float scale = 1.f;
  if (do_norm) {
    float ss = x * x;
    for (int off = 32; off > 0; off >>= 1) ss += __shfl_xor(ss, off);
    scale = 1.f / fmaxf(sqrtf(ss), 1e-12f);
  }
  float y = x * scale;
  long idx = (long)b * 256 + slice * 64 + lane;
  if (f32) ((float*)out)[idx] = y;
  else ((bf16*)out)[idx] = __float2bfloat16(y);
}

extern "C" void kernel_launch(void* const* d_in, const int* in_sizes, int n_in,
                              void* d_out, int out_size, void* d_ws, size_t ws_size,
                              hipStream_t stream) {
  const void* ue = d_in[0];
  const void* ie = d_in[1];
  const void* Wgc = d_in[2];
  const void* bgc = d_in[3];
  const void* Wbi = d_in[4];
  const void* bbi = d_in[5];
  const void* aval = d_in[6];
  const int* arow = (const int*)d_in[7];
  const int* acol = (const int*)d_in[8];
  const int* users = (const int*)d_in[9];
  const int* items = (const int*)d_in[10];

  char* ws = (char*)d_ws;
  size_t off = 0;
  float* ego32a = (float*)(ws + off); off += (size_t)N_NODES * D * 4;     // 38.4 MB
  u16* egobfa = (u16*)(ws + off);     off += (size_t)N_NODES * D * 2;     // 19.2 MB
  float* ego32b = (float*)(ws + off); off += (size_t)N_NODES * D * 4;     // 38.4 MB
  u16* egobfb = (u16*)(ws + off);     off += (size_t)N_NODES * D * 2;     // 19.2 MB
  int2* staged = (int2*)(ws + off);   off += (size_t)NBUCK * BCAP * 8;    // 42.0 MB
  int2* csr = (int2*)(ws + off);      off += (size_t)STG1 * 8;            // 39.4 MB (aliases level-1 staging)
  int* rp = (int*)(ws + off);         off += (size_t)(N_NODES + 64) * 4;
  int* bcnt = (int*)(ws + off);       off += (size_t)NBUCK * 4;
  int* scnt = (int*)(ws + off);       off += 64 * 4;                      // contiguous after bcnt
  int* bbase = (int*)(ws + off);      off += (size_t)(NBUCK + 64) * 4;
  int* flag = (int*)(ws + off);       off += 256;
  u16* wfrag = (u16*)(ws + off);      off += 3 * 8192 * 2;                // 48 KB frag-ordered weights
  float* biasws = (float*)(ws + off); off += 3 * 64 * 4;                  // combined bias
  u32* gmap = (u32*)(ws + off);       off += (size_t)GMW * 4;             // 18.8 KB gather bitmap
  int2* staged1 = csr;                // level-1 staging aliases csr (dead until sortbucket)
  (void)ws_size;

  k_zero<<<1, 64, 0, stream>>>(flag, 1);
  k_detect<<<1, 256, 0, stream>>>((const u16*)ue, flag);
  k_zero<<<(NBUCK + 64 + 255) / 256, 256, 0, stream>>>(bcnt, NBUCK + 64);  // bcnt + scnt
  k_mark<<<1, 1024, 0, stream>>>(users, items, gmap);
  k_prepw<<<3, 512, 0, stream>>>(Wgc, bgc, Wbi, bbi, wfrag, biasws, flag);
  k_init<<<(N_NODES * D / 4 + 255) / 256, 256, 0, stream>>>(ue, ie, ego32a, egobfa, flag, gmap);
  // slice 0 = raw (un-normalized) initial ego
  k_gather<<<2048, 256, 0, stream>>>(ego32a, users, items, d_out, 0, 0, flag);
  k_bin1<<<B1, 512, 0, stream>>>(arow, acol, aval, scnt, staged1, flag);
  k_bin2<<<B2, 512, 0, stream>>>(scnt, staged1, bcnt, staged);
  k_bucketbase<<<1, 1024, 0, stream>>>(bcnt, bbase);
  k_sortbucket<<<NBUCK, 512, 0, stream>>>(bcnt, staged, bbase, rp, csr);

  float* ei32 = ego32a; u16* eibf = egobfa;
  float* eo32 = ego32b; u16* eobf = egobfb;
  for (int k = 0; k < 3; ++k) {
    k_layer<<<NG, 256, 0, stream>>>(rp, csr, eibf, wfrag, biasws,
                                    eo32, eobf, k, gmap, (k == 2) ? 1 : 0);
    k_gather<<<2048, 256, 0, stream>>>(eo32, users, items, d_out, k + 1, 1, flag);
    float* t32 = ei32; ei32 = eo32; eo32 = t32;
    u16* tbf = eibf; eibf = eobf; eobf = tbf;
  }
}

// Round 13
// 446.493 us; speedup vs baseline: 1.1693x; 1.1336x over previous
//
#include <hip/hip_runtime.h>
#include <hip/hip_bf16.h>

// NGCF forward on MI355X.
// r20: LAYER-2 ROWLIST — compute only the 8192 gathered rows. History:
//  r16 fine-grain 1 tile per 4-wave block                       -> 527 (102us/layer)
//  r17 clean-round bins + prod-from-bf16                        -> 521 (100us/layer)
//  r18 column-block edge order                                  -> NULL (kept, harmless)
//  r19 dead-write elision via gather bitmap (WRITE 56->20.7MB)  -> 506 BEST (94.6us/layer)
// Regime (r19 confirmed): k_layer time tracks past-L2 traffic (~6.8TB/s
// marginal). Layer 2's output is read ONLY by the slice-3 gather (<=8192
// rows) -- the bitmap elides its dead writes but not the 94.5% dead COMPUTE
// + gather reads. r20: k_mark also emits rowlist[8192] (slot order);
// k_layer gains use_list mode (tile tg covers rowlist[tg*16..+16)); layer 2
// launches 512 blocks over the rowlist (5.5% of the work). Duplicate rows ->
// concurrent writes of BIT-IDENTICAL values (benign). Same compute path ->
// absmax unchanged. Layers 0/1 untouched (their egobf feeds next layer's
// gathers; neighbor set covers ~82% of rows -> no shrink possible).
// CSR build (r8/r9/r17/r18): two-level bucket binning with LDS repack, int4
// edge loads, reservation-atomic latency hidden, clean-round grids,
// (lr,col-block) sort key.

#define N_USER 100000
#define N_ITEM 50000
#define N_NODES 150000
#define NE 4800000
#define D 64
#define BROWS 128
#define NBUCK ((N_NODES + BROWS - 1) / BROWS)  // 1172
#define BCAP 4480                               // per-bucket: mean 4096 + 6 sigma
#define NG (N_NODES / 16)                       // 9375 row-tiles of 16 (exact)
#define NCB 5                                   // column-blocks of 32768 (col>>15)
#define NBIN (BROWS * NCB)                      // 640 sort bins
#define GMW ((N_NODES + 31) / 32)               // 4688 bitmap words
#define NGL (8192 / 16)                         // 512 rowlist tiles

// two-level binning
#define SUPSH 12                                // super = row >> 12 (4096 rows)
#define NSUP 37
#define SCAP 133120                             // per-super: mean 131072 + ~5.7 sigma
#define STG1 (NSUP * SCAP)                      // 4,925,440 >= NE
#define CH1 4688                                // edges per bin1 block -> B1 = 1024 EXACT
#define B1 ((NE + CH1 - 1) / CH1)               // 1024 = one clean resident round
#define CPS 27                                  // chunks per super (bin2)
#define CH2 4931                                // 27*4931 = 133137 >= SCAP
#define B2 (NSUP * CPS)                         // 999 blocks ~ one clean round

typedef __hip_bfloat16 bf16;
typedef unsigned short u16;
typedef unsigned int u32;
typedef __attribute__((ext_vector_type(8))) short short8;
typedef __attribute__((ext_vector_type(4))) float float4v;

__device__ __forceinline__ float bits2f(u16 u) {
  return __uint_as_float(((unsigned int)u) << 16);
}
__device__ __forceinline__ u16 f2bits(float x) {
  union { bf16 h; u16 u; } c;
  c.h = __float2bfloat16(x);
  return c.u;
}
__device__ __forceinline__ float loadF(const void* p, long i, int f32) {
  if (f32) return ((const float*)p)[i];
  return bits2f(((const u16*)p)[i]);
}

__global__ void k_zero(int* __restrict__ p, int n) {
  int i = blockIdx.x * blockDim.x + threadIdx.x;
  if (i < n) p[i] = 0;
}

// flag <- 1 if the float buffers are float32, 0 if bf16.
__global__ void k_detect(const u16* __restrict__ ue, int* __restrict__ flag) {
  int bad = 0;
  for (int t = threadIdx.x; t < 512; t += 256) {
    float f = fabsf(bits2f(ue[t]));
    if (!(f < 1e4f)) bad = 1;  // catches NaN/Inf too
  }
  if (bad) atomicOr(flag, 1);
}

// Build gather-set bitmap + slot rowlist. ONE block.
__global__ void __launch_bounds__(1024) k_mark(const int* __restrict__ users,
                                               const int* __restrict__ items,
                                               u32* __restrict__ gmap,
                                               int* __restrict__ rowlist) {
  int tid = threadIdx.x;
  for (int i = tid; i < GMW; i += 1024) gmap[i] = 0;
  __syncthreads();
  for (int b = tid; b < 8192; b += 1024) {
    int r = (b < 4096) ? users[b] : (N_USER + items[b - 4096]);
    rowlist[b] = r;
    atomicOr(&gmap[r >> 5], 1u << (r & 31));
  }
}

// Pre-pack frag-ordered bf16 weights (one block per layer) + combined bias.
// wfrag[layer][f]: f = ((t*4+s2)*64+lane)*8+j maps to W[k][n],
// k = s2*32+(lane>>4)*8+j (in [Wgc;Wbi]), n = t*16+(lane&15).
__global__ void k_prepw(const void* __restrict__ Wgc, const void* __restrict__ bgc,
                        const void* __restrict__ Wbi, const void* __restrict__ bbi,
                        u16* __restrict__ wfrag, float* __restrict__ biasws,
                        const int* __restrict__ flag) {
  int f32 = *flag;
  int layer = blockIdx.x;
  for (int f = threadIdx.x; f < 8192; f += 512) {
    int j = f & 7;
    int lane = (f >> 3) & 63;
    int s2 = (f >> 9) & 3;
    int t = f >> 11;
    int k = s2 * 32 + (lane >> 4) * 8 + j;
    int n = t * 16 + (lane & 15);
    float w = (k < 64) ? loadF(Wgc, (long)layer * 4096 + k * 64 + n, f32)
                       : loadF(Wbi, (long)layer * 4096 + (k - 64) * 64 + n, f32);
    wfrag[layer * 8192 + f] = f2bits(w);
  }
  if (threadIdx.x < 64)
    biasws[layer * 64 + threadIdx.x] =
        loadF(bgc, layer * 64 + threadIdx.x, f32) +
        loadF(bbi, layer * 64 + threadIdx.x, f32);
}

// ego32[N,64] fp32 (gather rows only) and egobf[N,64] bf16 (all rows).
__global__ void k_init(const void* __restrict__ ue, const void* __restrict__ ie,
                       float* __restrict__ ego32, u16* __restrict__ egobf,
                       const int* __restrict__ flag, const u32* __restrict__ gmap) {
  int f32 = *flag;
  int i4 = (blockIdx.x * blockDim.x + threadIdx.x) * 4;
  if (i4 >= N_NODES * D) return;
  const int UD = N_USER * D;
  float4 v;
  ushort4 b;
  if (f32) {
    const float* s = (i4 < UD) ? ((const float*)ue + i4) : ((const float*)ie + (i4 - UD));
    v = *(const float4*)s;
    b = make_ushort4(f2bits(v.x), f2bits(v.y), f2bits(v.z), f2bits(v.w));
  } else {
    const u16* s = (i4 < UD) ? ((const u16*)ue + i4) : ((const u16*)ie + (i4 - UD));
    b = *(const ushort4*)s;
    v = make_float4(bits2f(b.x), bits2f(b.y), bits2f(b.z), bits2f(b.w));
  }
  int r = i4 >> 6;
  if ((gmap[r >> 5] >> (r & 31)) & 1) *(float4*)(ego32 + i4) = v;
  *(ushort4*)(egobf + i4) = b;
}

// Level 1: bin a CH1-edge chunk into NSUP super-buckets. Scatter into LDS
// (counting-sort order by super), then write each super's run coalesced into
// staged1[super][SCAP]. Entry: (lr12<<18 | col, val_bits), lr12 = row & 4095.
__global__ void __launch_bounds__(512, 8) k_bin1(
    const int* __restrict__ row, const int* __restrict__ col,
    const void* __restrict__ val, int* __restrict__ scnt,
    int2* __restrict__ staged1, const int* __restrict__ flag) {
  __shared__ int2 sbuf[CH1];                 // 36.6 KB
  __shared__ int hist[NSUP];
  __shared__ int lstart[NSUP];
  __shared__ int gbase[NSUP];
  __shared__ int lcur[NSUP];
  int f32 = *flag;
  int tid = threadIdx.x;
  int e0 = blockIdx.x * CH1;
  int e1 = min(e0 + CH1, NE);               // e1-e0 always a multiple of 4
  if (tid < NSUP) hist[tid] = 0;
  __syncthreads();
  // pass 1: histogram over supers, 4 edges/thread (int4)
  for (int e = e0 + tid * 4; e < e1; e += 512 * 4) {
    int4 r4 = *(const int4*)(row + e);
    atomicAdd(&hist[r4.x >> SUPSH], 1);
    atomicAdd(&hist[r4.y >> SUPSH], 1);
    atomicAdd(&hist[r4.z >> SUPSH], 1);
    atomicAdd(&hist[r4.w >> SUPSH], 1);
  }
  __syncthreads();
  // wave 0: exclusive scan of hist; issue the global reservation atomic into
  // a register (committed to LDS only after the scatter -> latency hidden)
  int resv = 0;
  if (tid < 64) {
    int h = (tid < NSUP) ? hist[tid] : 0;
    int inc = h;
#pragma unroll
    for (int off = 1; off < 64; off <<= 1) {
      int v = __shfl_up(inc, off);
      if (tid >= off) inc += v;
    }
    if (tid < NSUP) {
      int ex = inc - h;
      lstart[tid] = ex;
      lcur[tid] = ex;
      if (h) resv = atomicAdd(&scnt[tid], h);
    }
  }
  __syncthreads();
  // pass 2: scatter into LDS in super-sorted order, 4 edges/thread
  for (int e = e0 + tid * 4; e < e1; e += 512 * 4) {
    int4 r4 = *(const int4*)(row + e);
    int4 c4 = *(const int4*)(col + e);
    int vb[4];
    if (f32) {
      float4 v4 = *(const float4*)((const float*)val + e);
      vb[0] = __float_as_int(v4.x); vb[1] = __float_as_int(v4.y);
      vb[2] = __float_as_int(v4.z); vb[3] = __float_as_int(v4.w);
    } else {
      ushort4 v4 = *(const ushort4*)((const u16*)val + e);
      vb[0] = __float_as_int(bits2f(v4.x)); vb[1] = __float_as_int(bits2f(v4.y));
      vb[2] = __float_as_int(bits2f(v4.z)); vb[3] = __float_as_int(bits2f(v4.w));
    }
    int rr[4] = {r4.x, r4.y, r4.z, r4.w};
    int cc[4] = {c4.x, c4.y, c4.z, c4.w};
#pragma unroll
    for (int j = 0; j < 4; ++j) {
      int s = rr[j] >> SUPSH;
      int pos = atomicAdd(&lcur[s], 1);
      sbuf[pos] = make_int2(((rr[j] & 4095) << 18) | cc[j], vb[j]);
    }
  }
  // commit reservations (atomic result consumed here, after scatter)
  if (tid < NSUP) gbase[tid] = resv;
  __syncthreads();
  // coalesced dense copy of each super's run; waves split the supers
  int wv = tid >> 6;
  int ln = tid & 63;
  for (int s = wv; s < NSUP; s += 8) {
    int h = hist[s];
    int gb = gbase[s];
    int ls = lstart[s];
    if (gb + h > SCAP) h = max(0, SCAP - gb);
    int2* dst = staged1 + (size_t)s * SCAP + gb;
    for (int i = ln; i < h; i += 64) dst[i] = sbuf[ls + i];
  }
}

// Level 2: re-bin one CH2-entry chunk of a super segment into its 32 row-
// buckets (global bucket = super*32 + (lr12>>7)), LDS repack, coalesced dense
// write into staged2[bucket][BCAP]. Output entry: (lr7<<18 | col, val_bits).
__global__ void __launch_bounds__(512, 8) k_bin2(
    const int* __restrict__ scnt, const int2* __restrict__ staged1,
    int* __restrict__ bcnt, int2* __restrict__ staged2) {
  __shared__ int2 sbuf[CH2];                 // 38.5 KB
  __shared__ int hist[32];
  __shared__ int lstart[32];
  __shared__ int gbase[32];
  __shared__ int lcur[32];
  int tid = threadIdx.x;
  int sup = blockIdx.x / CPS;
  int e0 = (blockIdx.x % CPS) * CH2;
  int n = min(scnt[sup], SCAP);
  int e1 = min(e0 + CH2, n);
  if (e0 >= e1) return;  // uniform across block
  const int2* seg = staged1 + (size_t)sup * SCAP;
  if (tid < 32) hist[tid] = 0;
  __syncthreads();
  // histogram, 2 entries/thread (int4 over int2 pairs); e1 may be odd
  {
    int e = e0 + tid * 2;
    for (; e + 1 < e1; e += 1024) {
      int4 two = *(const int4*)(seg + e);
      atomicAdd(&hist[two.x >> 25], 1);
      atomicAdd(&hist[two.z >> 25], 1);
    }
    if (e < e1) atomicAdd(&hist[seg[e].x >> 25], 1);
  }
  __syncthreads();
  int resv = 0;
  if (tid < 64) {
    int h = (tid < 32) ? hist[tid & 31] : 0;
    int inc = h;
#pragma unroll
    for (int off = 1; off < 32; off <<= 1) {
      int v = __shfl_up(inc, off);
      if (tid >= off) inc += v;
    }
    if (tid < 32) {
      int ex = inc - h;
      lstart[tid] = ex;
      lcur[tid] = ex;
      if (h) resv = atomicAdd(&bcnt[sup * 32 + tid], h);
    }
  }
  __syncthreads();
  // scatter into LDS in bucket-sorted order, 2 entries/thread
  {
    int e = e0 + tid * 2;
    for (; e + 1 < e1; e += 1024) {
      int4 two = *(const int4*)(seg + e);
      int lb0 = two.x >> 25;
      int p0 = atomicAdd(&lcur[lb0], 1);
      sbuf[p0] = make_int2(two.x & 0x01FFFFFF, two.y);
      int lb1 = two.z >> 25;
      int p1 = atomicAdd(&lcur[lb1], 1);
      sbuf[p1] = make_int2(two.z & 0x01FFFFFF, two.w);
    }
    if (e < e1) {
      int2 ent = seg[e];
      int lb = ent.x >> 25;
      int pos = atomicAdd(&lcur[lb], 1);
      sbuf[pos] = make_int2(ent.x & 0x01FFFFFF, ent.y);
    }
  }
  if (tid < 32) gbase[tid] = resv;
  __syncthreads();
  // coalesced dense copy of each bucket's run; waves split the buckets
  int wv = tid >> 6;
  int ln = tid & 63;
  for (int lb = wv; lb < 32; lb += 8) {
    int h = hist[lb];
    int gb = gbase[lb];
    int ls = lstart[lb];
    int b = sup * 32 + lb;
    if (b >= NBUCK) continue;       // unreachable given row bounds; safety
    if (gb + h > BCAP) h = max(0, BCAP - gb);
    int2* dst = staged2 + (size_t)b * BCAP + gb;
    for (int i = ln; i < h; i += 64) dst[i] = sbuf[ls + i];
  }
}

// Exclusive scan of per-bucket totals -> bbase[NBUCK]. One block of 1024.
__global__ void __launch_bounds__(1024) k_bucketbase(const int* __restrict__ bcnt,
                                                     int* __restrict__ bbase) {
  __shared__ int sh[2048];
  int tid = threadIdx.x;
  int t0 = (tid < NBUCK) ? min(bcnt[tid], BCAP) : 0;
  int i1 = 1024 + tid;
  int t1 = (i1 < NBUCK) ? min(bcnt[i1], BCAP) : 0;
  sh[tid] = t0;
  sh[i1] = t1;
  __syncthreads();
  for (int off = 1; off < 2048; off <<= 1) {
    int a0 = (tid >= off) ? sh[tid - off] : 0;
    int a1 = (i1 >= off) ? sh[i1 - off] : 0;
    __syncthreads();
    sh[tid] += a0;
    sh[i1] += a1;
    __syncthreads();
  }
  if (tid < NBUCK) bbase[tid] = sh[tid] - t0;       // exclusive
  if (i1 < NBUCK) bbase[i1] = sh[i1] - t1;
}

// One block per bucket: LDS counting sort of the bucket's staged edges by
// key (lr, col>>15) -- row-major, column-block minor. Rows stay contiguous
// (rp unchanged). hist reused in place as cursor -> LDS stays 38.4KB.
__global__ void __launch_bounds__(512, 8) k_sortbucket(
    const int* __restrict__ bcnt, const int2* __restrict__ staged,
    const int* __restrict__ bbase, int* __restrict__ rp, int2* __restrict__ csr) {
  __shared__ int2 sbuf[BCAP];      // 35.8 KB
  __shared__ int hist[NBIN];       // 2.56 KB; becomes cursor after scan
  int tid = threadIdx.x;
  int b = blockIdx.x;
  for (int i = tid; i < NBIN; i += 512) hist[i] = 0;
  __syncthreads();

  int n = min(bcnt[b], BCAP);
  const int2* seg = staged + (size_t)b * BCAP;
  {
    int e = tid * 2;
    for (; e + 1 < n; e += 1024) {
      int4 two = *(const int4*)(seg + e);
      atomicAdd(&hist[(two.x >> 18) * NCB + ((two.x >> 15) & 7)], 1);
      atomicAdd(&hist[(two.z >> 18) * NCB + ((two.z >> 15) & 7)], 1);
    }
    if (e < n) {
      int x = seg[e].x;
      atomicAdd(&hist[(x >> 18) * NCB + ((x >> 15) & 7)], 1);
    }
  }
  __syncthreads();

  // capture originals, then in-place inclusive Hillis-Steele scan over NBIN
  int i0 = tid, i1 = tid + 512;
  int h0 = hist[i0];
  int h1 = (i1 < NBIN) ? hist[i1] : 0;
  for (int off = 1; off < NBIN; off <<= 1) {
    int v0 = (i0 >= off) ? hist[i0 - off] : 0;
    int v1 = (i1 < NBIN && i1 >= off) ? hist[i1 - off] : 0;
    __syncthreads();
    hist[i0] += v0;
    if (i1 < NBIN) hist[i1] += v1;
    __syncthreads();
  }
  // hist -> exclusive starts (cursor)
  hist[i0] -= h0;
  if (i1 < NBIN) hist[i1] -= h1;
  __syncthreads();

  int base_b = bbase[b];
  if (tid < BROWS) {
    int r = b * BROWS + tid;
    if (r < N_NODES) rp[r] = base_b + hist[tid * NCB];  // row start = its first bin
  }
  if (b == 0 && tid == 0) rp[N_NODES] = NE;
  __syncthreads();   // rp reads done before scatter mutates cursor

  {
    int e = tid * 2;
    for (; e + 1 < n; e += 1024) {
      int4 two = *(const int4*)(seg + e);
      int k0 = (two.x >> 18) * NCB + ((two.x >> 15) & 7);
      int p0 = atomicAdd(&hist[k0], 1);
      if (p0 < BCAP) sbuf[p0] = make_int2(two.x & 0x3FFFF, two.y);
      int k1 = (two.z >> 18) * NCB + ((two.z >> 15) & 7);
      int p1 = atomicAdd(&hist[k1], 1);
      if (p1 < BCAP) sbuf[p1] = make_int2(two.z & 0x3FFFF, two.w);
    }
    if (e < n) {
      int2 ent = seg[e];
      int k = (ent.x >> 18) * NCB + ((ent.x >> 15) & 7);
      int pos = atomicAdd(&hist[k], 1);
      if (pos < BCAP) sbuf[pos] = make_int2(ent.x & 0x3FFFF, ent.y);
    }
  }
  __syncthreads();

  for (int i = tid; i < n; i += 512) csr[(size_t)base_b + i] = sbuf[i];
}

// FUSED layer (r16/r17/r19 structure + r20 rowlist mode): ONE 16-row tile
// per 4-wave 256-thread block. In use_list mode the tile's rows come from
// rowlist[tg*16..+16) (layer 2: only the 8192 gathered rows; duplicates ->
// concurrent identical writes, benign). Wave wv runs SpMM pass p=wv
// (quarter-wave per row, csr broadcast), deposits bf16 [side|prod] into the
// block-shared LDS tile (272B stride). __syncthreads, then wave wv computes
// its t=wv column-slice: 4 MFMAs (B-frags from L2-resident wfrag), writes
// cols [wv*16,+16). ego32_o gated by gather bitmap; egobf_o skipped when
// last. Written values bit-identical to r19.
__global__ void __launch_bounds__(256, 8) k_layer(
    const int* __restrict__ rp, const int2* __restrict__ csr,
    const u16* __restrict__ egobf_i,
    const u16* __restrict__ wfrag, const float* __restrict__ biasws,
    float* __restrict__ ego32_o, u16* __restrict__ egobf_o, int layer,
    const u32* __restrict__ gmap, int last,
    const int* __restrict__ rowlist, int use_list) {
  __shared__ u16 tile[2176];       // 16 rows x 136 u16 (272B stride), 4.25KB
  int tid = threadIdx.x;
  int lane = tid & 63;
  int ln = lane & 15;
  int quad = lane >> 4;            // 0..3
  int wv = tid >> 6;               // 0..3 = SpMM pass index = MFMA t-slice
  int tg = blockIdx.x;             // tile index (16 rows)
  const u16* wf = wfrag + layer * 8192;

  // ---- phase 1: SpMM pass wv (4 rows, quarter-wave per row) ----
  {
    int rid = tg * 16 + wv * 4 + quad;
    int r = use_list ? rowlist[rid] : rid;
    int s = rp[r];
    int e = rp[r + 1];
    float4 acc = make_float4(0.f, 0.f, 0.f, 0.f);
    int i = s;
    for (; i + 8 <= e; i += 8) {
      int2 cc[8];
#pragma unroll
      for (int t = 0; t < 8; ++t) cc[t] = csr[i + t];
      ushort4 gg[8];
#pragma unroll
      for (int t = 0; t < 8; ++t)
        gg[t] = *(const ushort4*)(egobf_i + (size_t)cc[t].x * 64 + ln * 4);
#pragma unroll
      for (int t = 0; t < 8; ++t) {
        float v = __int_as_float(cc[t].y);
        acc.x += v * bits2f(gg[t].x);
        acc.y += v * bits2f(gg[t].y);
        acc.z += v * bits2f(gg[t].z);
        acc.w += v * bits2f(gg[t].w);
      }
    }
    for (; i < e; ++i) {
      int2 c = csr[i];
      ushort4 g = *(const ushort4*)(egobf_i + (size_t)c.x * 64 + ln * 4);
      float v = __int_as_float(c.y);
      acc.x += v * bits2f(g.x);
      acc.y += v * bits2f(g.y);
      acc.z += v * bits2f(g.z);
      acc.w += v * bits2f(g.w);
    }
    // own-row ego from bf16
    ushort4 eb = *(const ushort4*)(egobf_i + (size_t)r * 64 + ln * 4);
    float4 er = make_float4(bits2f(eb.x), bits2f(eb.y), bits2f(eb.z), bits2f(eb.w));
    // deposit [side|prod] into shared tile row (wv*4+quad)
    u16* trow = tile + (wv * 4 + quad) * 136;
    *(ushort4*)(trow + ln * 4) =
        make_ushort4(f2bits(acc.x), f2bits(acc.y), f2bits(acc.z), f2bits(acc.w));
    *(ushort4*)(trow + 64 + ln * 4) =
        make_ushort4(f2bits(er.x * acc.x), f2bits(er.y * acc.y),
                     f2bits(er.z * acc.z), f2bits(er.w * acc.w));
  }
  __syncthreads();                 // tile complete across the 4 waves

  // ---- phase 2: wave wv computes t=wv slice: 16 rows x 16 cols ----
  float4v acc2 = (float4v){0.f, 0.f, 0.f, 0.f};
#pragma unroll
  for (int s2 = 0; s2 < 4; ++s2) {
    short8 A = *(const short8*)(tile + (size_t)ln * 136 + s2 * 32 + quad * 8);
    short8 Bf = *(const short8*)(wf + ((size_t)((wv * 4 + s2) * 64 + lane)) * 8);
    acc2 = __builtin_amdgcn_mfma_f32_16x16x32_bf16(A, Bf, acc2, 0, 0, 0);
  }
  int r0 = tg * 16;
  float bt = biasws[layer * 64 + wv * 16 + ln];
#pragma unroll
  for (int g2 = 0; g2 < 4; ++g2) {
    int rid2 = r0 + quad * 4 + g2;
    int rr = use_list ? rowlist[rid2] : rid2;
    float x = acc2[g2] + bt;
    x = fmaxf(x, 0.2f * x);        // leaky_relu(0.2)
    size_t idx = (size_t)rr * 64 + wv * 16 + ln;
    if ((gmap[rr >> 5] >> (rr & 31)) & 1) ego32_o[idx] = x;
    if (!last) egobf_o[idx] = f2bits(x);
  }
}

// gather 8192 output rows into out slice; optional l2-normalize per row.
__global__ void k_gather(const float* __restrict__ ego, const int* __restrict__ users,
                         const int* __restrict__ items, void* __restrict__ out,
                         int slice, int do_norm, const int* __restrict__ flag) {
  int f32 = *flag;
  int b = blockIdx.x * 4 + (threadIdx.x >> 6);
  int lane = threadIdx.x & 63;
  if (b >= 8192) return;
  int r = (b < 4096) ? users[b] : (N_USER + items[b - 4096]);
  float x = ego[(size_t)r * D + lane];
  float scale = 1.f;
  if (do_norm) {
    float ss = x * x;
    for (int off = 32; off > 0; off >>= 1) ss += __shfl_xor(ss, off);
    scale = 1.f / fmaxf(sqrtf(ss), 1e-12f);
  }
  float y = x * scale;
  long idx = (long)b * 256 + slice * 64 + lane;
  if (f32) ((float*)out)[idx] = y;
  else ((bf16*)out)[idx] = __float2bfloat16(y);
}

extern "C" void kernel_launch(void* const* d_in, const int* in_sizes, int n_in,
                              void* d_out, int out_size, void* d_ws, size_t ws_size,
                              hipStream_t stream) {
  const void* ue = d_in[0];
  const void* ie = d_in[1];
  const void* Wgc = d_in[2];
  const void* bgc = d_in[3];
  const void* Wbi = d_in[4];
  const void* bbi = d_in[5];
  const void* aval = d_in[6];
  const int* arow = (const int*)d_in[7];
  const int* acol = (const int*)d_in[8];
  const int* users = (const int*)d_in[9];
  const int* items = (const int*)d_in[10];

  char* ws = (char*)d_ws;
  size_t off = 0;
  float* ego32a = (float*)(ws + off); off += (size_t)N_NODES * D * 4;     // 38.4 MB
  u16* egobfa = (u16*)(ws + off);     off += (size_t)N_NODES * D * 2;     // 19.2 MB
  float* ego32b = (float*)(ws + off); off += (size_t)N_NODES * D * 4;     // 38.4 MB
  u16* egobfb = (u16*)(ws + off);     off += (size_t)N_NODES * D * 2;     // 19.2 MB
  int2* staged = (int2*)(ws + off);   off += (size_t)NBUCK * BCAP * 8;    // 42.0 MB
  int2* csr = (int2*)(ws + off);      off += (size_t)STG1 * 8;            // 39.4 MB (aliases level-1 staging)
  int* rp = (int*)(ws + off);         off += (size_t)(N_NODES + 64) * 4;
  int* bcnt = (int*)(ws + off);       off += (size_t)NBUCK * 4;
  int* scnt = (int*)(ws + off);       off += 64 * 4;                      // contiguous after bcnt
  int* bbase = (int*)(ws + off);      off += (size_t)(NBUCK + 64) * 4;
  int* flag = (int*)(ws + off);       off += 256;
  u16* wfrag = (u16*)(ws + off);      off += 3 * 8192 * 2;                // 48 KB frag-ordered weights
  float* biasws = (float*)(ws + off); off += 3 * 64 * 4;                  // combined bias
  u32* gmap = (u32*)(ws + off);       off += (size_t)GMW * 4;             // 18.8 KB gather bitmap
  int* rowlist = (int*)(ws + off);    off += 8192 * 4;                    // 32 KB slot rowlist
  int2* staged1 = csr;                // level-1 staging aliases csr (dead until sortbucket)
  (void)ws_size;

  k_zero<<<1, 64, 0, stream>>>(flag, 1);
  k_detect<<<1, 256, 0, stream>>>((const u16*)ue, flag);
  k_zero<<<(NBUCK + 64 + 255) / 256, 256, 0, stream>>>(bcnt, NBUCK + 64);  // bcnt + scnt
  k_mark<<<1, 1024, 0, stream>>>(users, items, gmap, rowlist);
  k_prepw<<<3, 512, 0, stream>>>(Wgc, bgc, Wbi, bbi, wfrag, biasws, flag);
  k_init<<<(N_NODES * D / 4 + 255) / 256, 256, 0, stream>>>(ue, ie, ego32a, egobfa, flag, gmap);
  // slice 0 = raw (un-normalized) initial ego
  k_gather<<<2048, 256, 0, stream>>>(ego32a, users, items, d_out, 0, 0, flag);
  k_bin1<<<B1, 512, 0, stream>>>(arow, acol, aval, scnt, staged1, flag);
  k_bin2<<<B2, 512, 0, stream>>>(scnt, staged1, bcnt, staged);
  k_bucketbase<<<1, 1024, 0, stream>>>(bcnt, bbase);
  k_sortbucket<<<NBUCK, 512, 0, stream>>>(bcnt, staged, bbase, rp, csr);

  float* ei32 = ego32a; u16* eibf = egobfa;
  float* eo32 = ego32b; u16* eobf = egobfb;
  for (int k = 0; k < 3; ++k) {
    int lastl = (k == 2) ? 1 : 0;
    int grid = lastl ? NGL : NG;
    k_layer<<<grid, 256, 0, stream>>>(rp, csr, eibf, wfrag, biasws,
                                      eo32, eobf, k, gmap, lastl,
                                      rowlist, lastl);
    k_gather<<<2048, 256, 0, stream>>>(eo32, users, items, d_out, k + 1, 1, flag);
    float* t32 = ei32; ei32 = eo32; eo32 = t32;
    u16* tbf = eibf; eibf = eobf; eobf = tbf;
  }
}